// Round 13
// baseline (415.180 us; speedup 1.0000x reference)
//
#include <hip/hip_runtime.h>
#include <hip/hip_fp16.h>

// out[n,a,b] = sigmoid(w2 . leaky(w1 . leaky(u'[n,a,:] - v[n,b,:]) + b1) + b2)
// u' = za.w0^T + b0, v = zb.w0^T (precomputed f16).
// Algebra: leaky(x) = 0.505x + 0.495|x|, so
//   w1.leaky(u-v) + b1 = [0.505(P[a,g]-Q[b,g]) + b1[g]] + (0.495 w1).|u-v|
// R13: 256-thr blocks (4 waves; gh bit picks g-half), grid 1024 ->
// occupancy quantum = 4 waves. Slim wave: w1f[16] stationary (64 regs) +
// single acc (16); v-slice in LDS (16 KB/block, shared); Ra/Sb/w2 transient
// epilogue loads. Target <=128 unified regs -> 4 waves/SIMD.
// Partials to pws; reduce kernel sums 8 (4 waves x 2 gh) + sigmoid.
// Fallback (small ws): R12-style 512-thr kernel with in-LDS reduce.

typedef float f32x16 __attribute__((ext_vector_type(16)));
typedef _Float16 f16x8 __attribute__((ext_vector_type(8)));
typedef int i32x4 __attribute__((ext_vector_type(4)));

// ---------------------------------------------------------------------------
// Merged pack kernel.
// Blocks 0..2047: row nr -> upack (f16), vpack (f16 frag-linear), and the
//   pq dots: Ra[nr,g] = 0.505*(u'.w1[g,:]) + b1[g], Sb[nr,g] = 0.505*(v.w1[g,:]).
// Blocks 2048..2303: 0.495*w1 into A-frag-linear f16.
// ---------------------------------------------------------------------------
__global__ __launch_bounds__(256) void pack_all(
    const float* __restrict__ za, const float* __restrict__ zb,
    const float* __restrict__ w0, const float* __restrict__ b0,
    const float* __restrict__ w1, const float* __restrict__ b1,
    _Float16* __restrict__ upack, _Float16* __restrict__ vpack,
    _Float16* __restrict__ w1pk,
    float* __restrict__ Ra, float* __restrict__ Sb) {
  int bid = blockIdx.x;
  int tid = threadIdx.x;
  if (bid < 2048) {
    int nr = bid;                   // n*256 + r
    int n = nr >> 8, r = nr & 255;
    __shared__ float arow[64], brow[64];
    __shared__ float ulds[256], vlds[256];
    if (tid < 64) arow[tid] = za[nr * 64 + tid];
    else if (tid < 128) brow[tid - 64] = zb[nr * 64 + (tid - 64)];
    __syncthreads();
    int h = tid;
    const float* w0r = w0 + h * 64;
    float ua = 0.f, vb = 0.f;
#pragma unroll
    for (int c = 0; c < 64; c += 4) {
      float4 w = *reinterpret_cast<const float4*>(w0r + c);
      ua += w.x * arow[c] + w.y * arow[c + 1] + w.z * arow[c + 2] + w.w * arow[c + 3];
      vb += w.x * brow[c] + w.y * brow[c + 1] + w.z * brow[c + 2] + w.w * brow[c + 3];
    }
    _Float16 uh = (_Float16)(ua + b0[h]);
    _Float16 vh = (_Float16)vb;
    upack[nr * 256 + h] = uh;
    // v B-frag-linear: frag (n, bblk=r>>5, kiter=h>>4); lane = lh*32 + (r&31)
    int bblk = r >> 5, lcol = r & 31;
    int kiter = h >> 4, rem = h & 15, lh2 = rem >> 3, j = rem & 7;
    vpack[(((n * 8 + bblk) * 16 + kiter) * 64 + lh2 * 32 + lcol) * 8 + j] = vh;
    // pq dots use the SAME f16-rounded values
    ulds[h] = (float)uh;
    vlds[h] = (float)vh;
    __syncthreads();
    int g = tid;
    const float* w1r = w1 + (size_t)g * 256;
    float au = 0.f, av = 0.f;
#pragma unroll 8
    for (int k = 0; k < 256; k += 4) {
      float4 w = *reinterpret_cast<const float4*>(w1r + k);
      au += w.x * ulds[k] + w.y * ulds[k + 1] + w.z * ulds[k + 2] + w.w * ulds[k + 3];
      av += w.x * vlds[k] + w.y * vlds[k + 1] + w.z * vlds[k + 2] + w.w * vlds[k + 3];
    }
    Ra[(size_t)nr * 256 + g] = 0.505f * au + b1[g];
    Sb[(size_t)nr * 256 + g] = 0.505f * av;
  } else {
    int id = (bid - 2048) * 256 + tid;   // 0..65535
    int g = id >> 8, k = id & 255;
    int gt = g >> 5, lcol = g & 31;
    int kiter = k >> 4, rem = k & 15, lh2 = rem >> 3, j = rem & 7;
    w1pk[((kiter * 8 + gt) * 64 + lh2 * 32 + lcol) * 8 + j] = (_Float16)(0.495f * w1[id]);
  }
}

// ---------------------------------------------------------------------------
// Main fused kernel (slim). Grid 1024 = mbid(n3|bblk3|aq3) x gh(1), 256 thr.
// Wave ws handles g-tile gt = gh*4+ws. v-slice staged in LDS once.
// ---------------------------------------------------------------------------
__global__ __launch_bounds__(256, 4) void fused_main(
    const _Float16* __restrict__ upack, const _Float16* __restrict__ vpack,
    const _Float16* __restrict__ w1pk,
    const float* __restrict__ Ra, const float* __restrict__ Sb,
    const float* __restrict__ w2, float* __restrict__ pws) {
  __shared__ _Float16 vsh[8192];    // 16 KB, frag-linear v slice for (n,bblk)
  int bid = blockIdx.x;
  int gh = bid & 1;
  int mbid = bid >> 1;              // n(3b)|bblk(3b)|aq(3b)
  int aq = mbid & 7;
  int bblk = (mbid >> 3) & 7;
  int n = mbid >> 6;
  int tid = threadIdx.x;
  int ws = tid >> 6;                // 0..3
  int gt = gh * 4 + ws;             // g-tile (32 g)
  int l = tid & 63;
  int l31 = l & 31, lh = l >> 5;

  // Stage v slice (8192 f16): 4 x 16B per thread, linear.
  {
    const f16x8* vsrc = reinterpret_cast<const f16x8*>(
        vpack + (size_t)((n * 8 + bblk) * 16) * 512);
    f16x8* vdst = reinterpret_cast<f16x8*>(vsh);
    vdst[tid] = vsrc[tid];
    vdst[tid + 256] = vsrc[tid + 256];
    vdst[tid + 512] = vsrc[tid + 512];
    vdst[tid + 768] = vsrc[tid + 768];
  }
  // Stationary 0.495*w1 A-fragments for gt: 64 regs.
  f16x8 w1f[16];
#pragma unroll
  for (int kt = 0; kt < 16; ++kt)
    w1f[kt] = *reinterpret_cast<const f16x8*>(w1pk + ((kt * 8 + gt) * 64 + l) * 8);
  __syncthreads();

  const _Float16* ub = upack + (size_t)(n * 256 + aq * 32) * 256 + lh * 8;
  const float* rab = Ra + (size_t)(n * 256 + aq * 32) * 256;
  const float* sbrow = Sb + (size_t)(n * 256 + bblk * 32 + l31) * 256;
  float* pw = pws + ((size_t)(mbid * 32) * 8 + gh * 4 + ws) * 32;

  for (int it = 0; it < 32; ++it) {
    const _Float16* ur = ub + (size_t)it * 256;

    f32x16 acc;
#pragma unroll
    for (int r = 0; r < 16; ++r) acc[r] = 0.f;

#pragma unroll
    for (int kt = 0; kt < 16; ++kt) {
      f16x8 uu = *reinterpret_cast<const f16x8*>(ur + kt * 16);
      f16x8 vv = *reinterpret_cast<const f16x8*>(vsh + kt * 512 + l * 8);
      f16x8 d = uu - vv;                       // 4x v_pk_add_f16
      i32x4 di = __builtin_bit_cast(i32x4, d);
      di &= 0x7fff7fff;                        // |d|
      acc = __builtin_amdgcn_mfma_f32_32x32x16_f16(
          w1f[kt], __builtin_bit_cast(f16x8, di), acc, 0, 0, 0);
    }

    // Epilogue: s = acc + Ra - Sb; h = leaky(s); p = sum h*w2 (16 g in-lane).
    const float* rar = rab + (size_t)it * 256;
    float p = 0.f;
#pragma unroll
    for (int rg = 0; rg < 4; ++rg) {
      int gb = gt * 32 + 8 * rg + 4 * lh;
      float4 rr = *reinterpret_cast<const float4*>(rar + gb);
      float4 ss = *reinterpret_cast<const float4*>(sbrow + gb);
      float4 ww = *reinterpret_cast<const float4*>(w2 + gb);
      float s, h;
      s = acc[4 * rg + 0] + rr.x - ss.x; h = fmaxf(s, 0.01f * s); p = fmaf(h, ww.x, p);
      s = acc[4 * rg + 1] + rr.y - ss.y; h = fmaxf(s, 0.01f * s); p = fmaf(h, ww.y, p);
      s = acc[4 * rg + 2] + rr.z - ss.z; h = fmaxf(s, 0.01f * s); p = fmaf(h, ww.z, p);
      s = acc[4 * rg + 3] + rr.w - ss.w; h = fmaxf(s, 0.01f * s); p = fmaf(h, ww.w, p);
    }
    p += __shfl_xor(p, 32, 64);     // fold lh halves (g split by lh)
    if (l < 32) pw[(size_t)it * 256 + l31] = p;
  }
}

// ---------------------------------------------------------------------------
// Reduce kernel: out = sigmoid(sum_8 partials + b2).
// ---------------------------------------------------------------------------
__global__ __launch_bounds__(256) void reduce_kernel(
    const float* __restrict__ pws, const float* __restrict__ b2,
    float* __restrict__ out) {
  int o = blockIdx.x * 256 + threadIdx.x;     // (n,a,b) flat
  int n = o >> 16, a = (o >> 8) & 255, b = o & 255;
  int bblk = b >> 5, b32 = b & 31, aq = a >> 5, it = a & 31;
  int mbid = (n << 6) | (bblk << 3) | aq;
  const float* p = pws + (((size_t)mbid * 32 + it) * 8) * 32 + b32;
  float s = b2[0];
#pragma unroll
  for (int w = 0; w < 8; ++w) s += p[w * 32];
  out[o] = 1.f / (1.f + __expf(-s));
}

// ---------------------------------------------------------------------------
// Fallback (small ws): R12-style 512-thr kernel, both stationaries, LDS reduce.
// ---------------------------------------------------------------------------
__global__ __launch_bounds__(512, 2) void fused_fb(
    const _Float16* __restrict__ upack, const _Float16* __restrict__ vpack,
    const _Float16* __restrict__ w1pk,
    const float* __restrict__ Ra, const float* __restrict__ Sb,
    const float* __restrict__ w2, const float* __restrict__ b2,
    float* __restrict__ out) {
  __shared__ float lds_p[2][4][8][32];
  int bid = blockIdx.x;             // n(3b)|bblk(3b)|aq(3b)
  int n = bid >> 6;
  int bblk = (bid >> 3) & 7;
  int aq = bid & 7;
  int tid = threadIdx.x;
  int ws = tid >> 6;
  int l = tid & 63;
  int l31 = l & 31, lh = l >> 5;

  f16x8 w1f[16];
#pragma unroll
  for (int kt = 0; kt < 16; ++kt)
    w1f[kt] = *reinterpret_cast<const f16x8*>(w1pk + ((kt * 8 + ws) * 64 + l) * 8);
  const _Float16* vbase = vpack + (size_t)((n * 8 + bblk) * 16) * 512 + l * 8;
  f16x8 vf[16];
#pragma unroll
  for (int kt = 0; kt < 16; ++kt)
    vf[kt] = *reinterpret_cast<const f16x8*>(vbase + kt * 512);

  float sbf[16], w2f[16];
  const float* sbrow = Sb + (size_t)(n * 256 + bblk * 32 + l31) * 256;
#pragma unroll
  for (int rg = 0; rg < 4; ++rg) {
    int gbase = ws * 32 + 8 * rg + 4 * lh;
    float4 ss = *reinterpret_cast<const float4*>(sbrow + gbase);
    float4 ww = *reinterpret_cast<const float4*>(w2 + gbase);
    sbf[4 * rg + 0] = ss.x; sbf[4 * rg + 1] = ss.y;
    sbf[4 * rg + 2] = ss.z; sbf[4 * rg + 3] = ss.w;
    w2f[4 * rg + 0] = ww.x; w2f[4 * rg + 1] = ww.y;
    w2f[4 * rg + 2] = ww.z; w2f[4 * rg + 3] = ww.w;
  }
  float b2v = b2[0];

  const _Float16* ub = upack + (size_t)(n * 256 + aq * 32) * 256 + lh * 8;
  const float* rabase = Ra + (size_t)(n * 256 + aq * 32) * 256;

  for (int bt = 0; bt < 8; ++bt) {
    int ph = bt & 1;
    for (int j = 0; j < 4; ++j) {
      int it = bt * 4 + j;
      const _Float16* ur = ub + (size_t)it * 256;
      const float* rar = rabase + (size_t)it * 256;
      f32x16 accA;
#pragma unroll
      for (int rg = 0; rg < 4; ++rg) {
        float4 rr = *reinterpret_cast<const float4*>(rar + ws * 32 + 8 * rg + 4 * lh);
        accA[4 * rg + 0] = rr.x - sbf[4 * rg + 0];
        accA[4 * rg + 1] = rr.y - sbf[4 * rg + 1];
        accA[4 * rg + 2] = rr.z - sbf[4 * rg + 2];
        accA[4 * rg + 3] = rr.w - sbf[4 * rg + 3];
      }
#pragma unroll
      for (int kt = 0; kt < 16; ++kt) {
        f16x8 uu = *reinterpret_cast<const f16x8*>(ur + kt * 16);
        f16x8 d = uu - vf[kt];
        i32x4 di = __builtin_bit_cast(i32x4, d);
        di &= 0x7fff7fff;
        accA = __builtin_amdgcn_mfma_f32_32x32x16_f16(
            w1f[kt], __builtin_bit_cast(f16x8, di), accA, 0, 0, 0);
      }
      float p = 0.f;
#pragma unroll
      for (int r = 0; r < 16; ++r) {
        float s = accA[r];
        float h = fmaxf(s, 0.01f * s);
        p = fmaf(h, w2f[r], p);
      }
      p += __shfl_xor(p, 32, 64);
      if (l < 32) lds_p[ph][j][ws][l31] = p;
    }
    __syncthreads();
    if (tid < 128) {
      int al = tid >> 5, b = tid & 31;
      float s = b2v;
#pragma unroll
      for (int w = 0; w < 8; ++w) s += lds_p[ph][al][w][b];
      int a = aq * 32 + bt * 4 + al;
      out[(size_t)(n * 256 + a) * 256 + bblk * 32 + b] = 1.f / (1.f + __expf(-s));
    }
  }
}

extern "C" void kernel_launch(void* const* d_in, const int* in_sizes, int n_in,
                              void* d_out, int out_size, void* d_ws, size_t ws_size,
                              hipStream_t stream) {
  const float* za = (const float*)d_in[0];
  const float* zb = (const float*)d_in[1];
  const float* w0 = (const float*)d_in[2];
  const float* b0 = (const float*)d_in[3];
  const float* w1 = (const float*)d_in[4];
  const float* b1 = (const float*)d_in[5];
  const float* w2 = (const float*)d_in[6];
  const float* b2 = (const float*)d_in[7];
  float* out = (float*)d_out;

  char* ws = (char*)d_ws;
  _Float16* upack = (_Float16*)ws;                        // 1 MB   @ 0
  _Float16* vpack = (_Float16*)(ws + (1u << 20));         // 1 MB   @ 1M
  _Float16* w1pk  = (_Float16*)(ws + (2u << 20));         // 128 KB @ 2M
  float*    Ra    = (float*)(ws + (4u << 20));            // 2 MB   @ 4M
  float*    Sb    = (float*)(ws + (6u << 20));            // 2 MB   @ 6M
  float*    pws   = (float*)(ws + (8u << 20));            // 16 MB  @ 8M

  pack_all<<<2304, 256, 0, stream>>>(za, zb, w0, b0, w1, b1,
                                     upack, vpack, w1pk, Ra, Sb);

  const size_t need = (24ull << 20);   // 8 MB + 16 MB pws
  if (ws_size >= need) {
    fused_main<<<1024, 256, 0, stream>>>(upack, vpack, w1pk, Ra, Sb, w2, pws);
    reduce_kernel<<<2048, 256, 0, stream>>>(pws, b2, out);
  } else {
    fused_fb<<<512, 512, 0, stream>>>(upack, vpack, w1pk, Ra, Sb, w2, b2, out);
  }
}